// Round 1
// 359.283 us; speedup vs baseline: 1.0298x; 1.0298x over previous
//
#include <hip/hip_runtime.h>

// SelfAttnHead: B=4, T=2048, E=1024, H=2048. fp32 in/out, bf16 MFMA internally.
// out = softmax_axis1((q q^T / sqrt(H)) * tril) @ v,  q = x Wq + bq, v = x Wv + bv
// attn[q,k] = e[q,k]/s[k], e = exp(masked logits); masked (q<k) entries = exp(0) = 1.
// s[k] = column sum. Fold 1/s into v' = v/s. Triangular decomposition:
//   out[q,h] = sum_{k<K_end} P[q,k] v'[k,h] + sfx[h],  K_end=(rt+1)*256.
// This round: projection + PV GEMMs ported to a 256x256-tile, 512-thread,
// 4-deep-buffer pipeline (BK=32): counted s_waitcnt vmcnt(8) (never 0 in
// steady state), raw s_barrier, setprio around 16-MFMA clusters, XOR-swizzled
// conflict-free LDS.  Scores GEMM keeps the verified 128^2 kernel.

#define B_DIM 4
#define T_DIM 2048
#define E_DIM 1024
#define H_DIM 2048

typedef __attribute__((ext_vector_type(8))) short bf16x8;
typedef __attribute__((ext_vector_type(4))) short s16x4;
typedef __attribute__((ext_vector_type(4))) float f32x4;

__device__ __forceinline__ float bf2f(short s) {
  union { float f; unsigned u; } x; x.u = ((unsigned)(unsigned short)s) << 16; return x.f;
}
__device__ __forceinline__ short f2bf(float f) {
  union { float f; unsigned u; } x; x.f = f;
  unsigned r = x.u + 0x7fff + ((x.u >> 16) & 1);  // RNE
  return (short)(r >> 16);
}

__device__ __forceinline__ void gload16(const short* g, short* l) {
  __builtin_amdgcn_global_load_lds(
      (const __attribute__((address_space(1))) void*)g,
      (__attribute__((address_space(3))) void*)l, 16, 0, 0);
}

// ============================================================================
// 256x256-tile deep-pipelined GEMM:  C[m,n] = sum_k A[m,k]*B[n,k]
// 512 threads = 8 waves (2 M-waves x 4 N-waves), per-wave output 128x64.
// BK=32, 4 LDS buffers (128 KiB), staging 3 K-steps ahead; per K-step:
//   P0: read A[m0-3](4xb128)+B[n0-3](4xb128); stage A-halves of step t+3;
//       s_barrier; setprio(1); 16 MFMA; setprio(0); s_barrier
//   P1: read A[m4-7](4xb128); stage B-halves of t+3; s_barrier; setprio(1);
//       16 MFMA; setprio(0); lgkmcnt(0); vmcnt(8|4|0); s_barrier
// vmcnt(8) retires exactly the next step's 4 half-tiles (8 stay in flight).
// LDS swizzle: slot = chunk ^ ((row>>2)&3)  (2-way max on ds_read_b128, free;
// global source pre-swizzled so global_load_lds dest stays linear).
// MODE 0: dual-output projection, grid (N/256, M/256, 1). 256-col tiles never
//         straddle N/2: ct<8 -> Cg/bias else Cg2/bias2. bf16 out via LDS repack.
// MODE 2: fp32 out + sfx[2rt+1][col] added; K-loop ends at (rt+1)*256.
//         grid (M/256, N/256, B). 256 blocks -> 1/CU, all co-resident.
// ============================================================================
template<int MODE>
__global__ __launch_bounds__(512, 2) void gemm256(
    const short* __restrict__ Ag, const short* __restrict__ Bg,
    const float* __restrict__ bias, const float* __restrict__ bias2,
    void* __restrict__ Cg, void* __restrict__ Cg2,
    const float* __restrict__ sfx,
    int N, int K, long sA, long sB, long sC)
{
  __shared__ __align__(16) short lds[4 * 16384];  // buf b: A @ b*16384, B @ +8192

  const int t = threadIdx.x;
  const int lane = t & 63, wave = t >> 6;
  const int wm = wave >> 2, wn = wave & 3;
  const int l16 = lane & 15, kg = lane >> 4;

  int rt, ct, bz;
  if (MODE == 2) { rt = blockIdx.x; ct = blockIdx.y; bz = blockIdx.z; }
  else           { rt = blockIdx.y; ct = blockIdx.x; bz = 0; }

  const short* A  = Ag + (long)bz * sA + (long)rt * 256 * K;
  const short* Bp = Bg + (long)bz * sB + (long)ct * 256 * K;
  const int kEnd = (MODE == 2) ? (rt + 1) * 256 : K;
  const int NT = kEnd >> 5;  // BK=32 steps (>= 8 for all uses)

  // staging addresses: thread t covers LDS bytes t*16 of each 8 KiB half
  // (128 rows x 32 cols). row = t>>2, slot = t&3, src chunk = slot ^ f(row).
  const int sr = t >> 2;
  const int scg = (t & 3) ^ ((sr >> 2) & 3);
  const long a0 = (long)sr * K + scg * 8;
  const long a1 = a0 + 128L * K;

  // fragment-read addresses: chunk kg of row -> slot kg ^ ((l16>>2)&3)
  const int swz = kg ^ ((l16 >> 2) & 3);
  const int aoff = (wm * 128 + l16) * 32 + swz * 8;
  const int boff = (wn * 64 + l16) * 32 + swz * 8;

  f32x4 acc[8][4] = {};

  // prologue: stage steps 0..2 (12 loads in flight), land step 0
#pragma unroll
  for (int s = 0; s < 3; ++s) {
    short* L = &lds[s * 16384];
    const long k0 = (long)s * 32;
    gload16(A + a0 + k0, L + t * 8);
    gload16(A + a1 + k0, L + 4096 + t * 8);
    gload16(Bp + a0 + k0, L + 8192 + t * 8);
    gload16(Bp + a1 + k0, L + 12288 + t * 8);
  }
  asm volatile("s_waitcnt vmcnt(8)" ::: "memory");
  __builtin_amdgcn_s_barrier();

  for (int ts = 0; ts < NT; ++ts) {
    const short* Ab = &lds[(ts & 3) * 16384];
    const short* Bb = Ab + 8192;
    short* Ls = &lds[((ts + 3) & 3) * 16384];
    const long k3 = (long)(ts + 3) * 32;
    const bool st = (ts + 3) < NT;

    bf16x8 bfrag[4], afrag[4];
    // ---- phase 0: m0-3 x n0-3 ----
#pragma unroll
    for (int n = 0; n < 4; ++n) bfrag[n] = *(const bf16x8*)&Bb[boff + n * 512];
#pragma unroll
    for (int m = 0; m < 4; ++m) afrag[m] = *(const bf16x8*)&Ab[aoff + m * 512];
    if (st) {
      gload16(A + a0 + k3, Ls + t * 8);
      gload16(A + a1 + k3, Ls + 4096 + t * 8);
    }
    __builtin_amdgcn_s_barrier();
    __builtin_amdgcn_s_setprio(1);
#pragma unroll
    for (int m = 0; m < 4; ++m)
#pragma unroll
      for (int n = 0; n < 4; ++n)
        acc[m][n] = __builtin_amdgcn_mfma_f32_16x16x32_bf16(afrag[m], bfrag[n], acc[m][n], 0, 0, 0);
    __builtin_amdgcn_s_setprio(0);
    __builtin_amdgcn_s_barrier();
    // ---- phase 1: m4-7 x n0-3 (B frags reused) ----
#pragma unroll
    for (int m = 0; m < 4; ++m) afrag[m] = *(const bf16x8*)&Ab[aoff + (m + 4) * 512];
    if (st) {
      gload16(Bp + a0 + k3, Ls + 8192 + t * 8);
      gload16(Bp + a1 + k3, Ls + 12288 + t * 8);
    }
    __builtin_amdgcn_s_barrier();
    __builtin_amdgcn_s_setprio(1);
#pragma unroll
    for (int m = 0; m < 4; ++m)
#pragma unroll
      for (int n = 0; n < 4; ++n)
        acc[m + 4][n] = __builtin_amdgcn_mfma_f32_16x16x32_bf16(afrag[m], bfrag[n], acc[m + 4][n], 0, 0, 0);
    __builtin_amdgcn_s_setprio(0);
    // retire this step's LDS reads, land next step's tiles (keep rest in flight)
    asm volatile("s_waitcnt lgkmcnt(0)" ::: "memory");
    const int w = NT - 2 - ts;  // steps staged beyond ts+1
    if (w >= 2)      asm volatile("s_waitcnt vmcnt(8)" ::: "memory");
    else if (w == 1) asm volatile("s_waitcnt vmcnt(4)" ::: "memory");
    else if (w == 0) asm volatile("s_waitcnt vmcnt(0)" ::: "memory");
    __builtin_amdgcn_s_barrier();
  }

  __syncthreads();  // full drain before LDS reuse / exit

  if (MODE == 0) {
    // repack to bf16 in LDS (256x256 = 128 KiB exactly), row-XOR swizzle so
    // neither the 2B scatter writes nor the b128 column reads 32-way conflict.
    short* Cs = lds;
    const int Nh = N >> 1;
#pragma unroll
    for (int m = 0; m < 8; ++m)
#pragma unroll
      for (int n = 0; n < 4; ++n) {
        const int cl = wn * 64 + n * 16 + l16;
        const int colg = ct * 256 + cl;
        const float bv = (colg < Nh) ? bias[colg] : bias2[colg - Nh];
#pragma unroll
        for (int r = 0; r < 4; ++r) {
          const int rl = wm * 128 + m * 16 + kg * 4 + r;
          *(short*)((char*)Cs + (((((rl << 8) + cl) << 1)) ^ ((rl & 7) << 4))) =
              f2bf(acc[m][n][r] + bv);
        }
      }
    __syncthreads();
    short* C = ((ct * 256) < Nh) ? (short*)Cg : (short*)Cg2;
    const int rr = t >> 1, hc = (t & 1) * 128;
    const long gbase = (long)(rt * 256 + rr) * Nh + ((ct * 256) & (Nh - 1)) + hc;
#pragma unroll
    for (int j = 0; j < 16; ++j)
      *(bf16x8*)(C + gbase + j * 8) =
          *(const bf16x8*)((const char*)Cs +
              ((((rr << 8) + hc + (j << 3)) << 1) ^ ((rr & 7) << 4)));
  } else {
    // fp32 direct stores (64B segments per l16 group) + suffix constant
    float* C = (float*)Cg + (long)bz * sC;
    const float* sf = sfx + ((long)bz * 16 + 2 * rt + 1) * N;
    const int rowb = rt * 256 + wm * 128 + kg * 4;
    const int colb = ct * 256 + wn * 64 + l16;
#pragma unroll
    for (int m = 0; m < 8; ++m)
#pragma unroll
      for (int n = 0; n < 4; ++n) {
        const int col = colb + n * 16;
        const float s = sf[col];
#pragma unroll
        for (int r = 0; r < 4; ++r)
          C[(long)(rowb + m * 16 + r) * N + col] = acc[m][n][r] + s;
      }
  }
}

// ============================================================================
// verified 128^2 kernel, kept for the scores pass (MODE 1 only this round)
// ============================================================================
template<int MODE>
__global__ __launch_bounds__(256) void gemm_bt(
    const short* __restrict__ Ag, const short* __restrict__ Bg,
    const float* __restrict__ bias, const float* __restrict__ bias2,
    void* __restrict__ Cg, void* __restrict__ Cg2,
    float* __restrict__ colsum, const float* __restrict__ sfx,
    int M, int N, int K, long sA, long sB, long sC, float scale)
{
  __shared__ __align__(16) short lds[128 * 64 * 2];  // As | Bs; reused as Cs
  short* As = lds;
  short* Bs = lds + 128 * 64;
  __shared__ float csum[128];

  const int t = threadIdx.x;
  const int bz = blockIdx.z;

  int rt, ct;
  if (MODE == 1) {
    int idx = 135 - blockIdx.x;  // heavy (large-rt) tiles dispatch first
    rt = (int)((sqrtf(8.0f * idx + 1.0f) - 1.0f) * 0.5f);
    while ((rt + 1) * (rt + 2) / 2 <= idx) rt++;
    while (rt * (rt + 1) / 2 > idx) rt--;
    ct = idx - rt * (rt + 1) / 2;
  } else if (MODE == 2) {
    rt = (gridDim.x - 1) - blockIdx.x;
    ct = blockIdx.y;
  } else {
    rt = blockIdx.y; ct = blockIdx.x;
  }

  const short* A = Ag + (long)bz * sA + (long)rt * 128 * K;
  const short* B = Bg + (long)bz * sB + (long)ct * 128 * K;
  const int kEnd = (MODE == 2) ? (rt + 1) * 128 : K;

  const int lane = t & 63;
  const int wave = t >> 6;
  const int wr = wave >> 1, wc = wave & 1;
  const int l16 = lane & 15, kg = lane >> 4;

  if (MODE == 1) { if (t < 128) csum[t] = (rt == ct) ? 128.0f * ct : 0.0f; }

  f32x4 acc[4][4] = {};

  for (int k0 = 0; k0 < kEnd; k0 += 64) {
    __syncthreads();
#pragma unroll
    for (int j = 0; j < 4; ++j) {
      const int e = j * 256 + t;
      const int r = e >> 3, cl = e & 7;
      const int cg = cl ^ (r & 7);
      gload16(A + (long)r * K + (k0 + cg * 8), &As[e * 8]);
      gload16(B + (long)r * K + (k0 + cg * 8), &Bs[e * 8]);
    }
    __syncthreads();
#pragma unroll
    for (int kk = 0; kk < 2; ++kk) {
      bf16x8 af[4], bfr[4];
#pragma unroll
      for (int mi = 0; mi < 4; ++mi)
        af[mi] = *(const bf16x8*)&As[(wr * 64 + mi * 16 + l16) * 64 +
                                     ((kk * 4 + kg) ^ (l16 & 7)) * 8];
#pragma unroll
      for (int ni = 0; ni < 4; ++ni)
        bfr[ni] = *(const bf16x8*)&Bs[(wc * 64 + ni * 16 + l16) * 64 +
                                      ((kk * 4 + kg) ^ (l16 & 7)) * 8];
#pragma unroll
      for (int mi = 0; mi < 4; ++mi)
#pragma unroll
        for (int ni = 0; ni < 4; ++ni)
          acc[mi][ni] = __builtin_amdgcn_mfma_f32_16x16x32_bf16(af[mi], bfr[ni], acc[mi][ni], 0, 0, 0);
    }
  }

  if (MODE == 1) {
    short* Cs = lds;  // 128x128 bf16 tile
    __syncthreads();
    float ps[4] = {0.f, 0.f, 0.f, 0.f};
#pragma unroll
    for (int mi = 0; mi < 4; ++mi)
#pragma unroll
      for (int ni = 0; ni < 4; ++ni) {
        const int cl = wc * 64 + ni * 16 + l16;
        const int col = ct * 128 + cl;
#pragma unroll
        for (int r = 0; r < 4; ++r) {
          const int rl = wr * 64 + kg * 4 + mi * 16 + r;
          const int row = rt * 128 + rl;
          float e = (row >= col) ? __expf(acc[mi][ni][r] * scale) : 1.0f;
          Cs[rl * 128 + cl] = f2bf(e);
          ps[ni] += e;
        }
      }
#pragma unroll
    for (int ni = 0; ni < 4; ++ni)
      atomicAdd(&csum[wc * 64 + ni * 16 + l16], ps[ni]);
    __syncthreads();
    short* C = (short*)Cg + (long)bz * sC;
    const int rr = t >> 1, cc = (t & 1) * 64;
    const long gbase = (long)(rt * 128 + rr) * N + ct * 128 + cc;
#pragma unroll
    for (int j = 0; j < 8; ++j)
      *(bf16x8*)(C + gbase + j * 8) = *(const bf16x8*)&Cs[rr * 128 + cc + j * 8];
    if (t < 128)
      atomicAdd(&colsum[(long)bz * N + ct * 128 + t], csum[t]);
  } else if (MODE == 0) {
    short* Cs = lds;
    __syncthreads();
    const int Nh = N >> 1;
#pragma unroll
    for (int mi = 0; mi < 4; ++mi)
#pragma unroll
      for (int ni = 0; ni < 4; ++ni) {
        const int cl = wc * 64 + ni * 16 + l16;
        const int colg = ct * 128 + cl;
        const float bv = (colg < Nh) ? bias[colg] : bias2[colg - Nh];
#pragma unroll
        for (int r = 0; r < 4; ++r) {
          const int rl = wr * 64 + kg * 4 + mi * 16 + r;
          Cs[rl * 128 + cl] = f2bf(acc[mi][ni][r] + bv);
        }
      }
    __syncthreads();
    short* C = (ct * 128 < Nh) ? (short*)Cg : (short*)Cg2;
    const int colofs = (ct * 128) & (Nh - 1);
    const int rr = t >> 1, cc = (t & 1) * 64;
    const long gbase = (long)(rt * 128 + rr) * Nh + colofs + cc;
#pragma unroll
    for (int j = 0; j < 8; ++j)
      *(bf16x8*)(C + gbase + j * 8) = *(const bf16x8*)&Cs[rr * 128 + cc + j * 8];
  } else {
    const int rowb = rt * 128 + wr * 64 + kg * 4;
    const int colb = ct * 128 + wc * 64 + l16;
    float* C = (float*)Cg + (long)bz * sC;
    const float* sf = sfx + ((long)bz * 16 + rt) * N;
#pragma unroll
    for (int mi = 0; mi < 4; ++mi)
#pragma unroll
      for (int ni = 0; ni < 4; ++ni) {
        int col = colb + ni * 16;
        float s = sf[col];
#pragma unroll
        for (int r = 0; r < 4; ++r) {
          int row = rowb + mi * 16 + r;
          C[(long)row * N + col] = acc[mi][ni][r] + s;
        }
      }
  }
}

// all-ones 128x128 bf16 tiles at (row-tile 2r, col-tile 2r+1) of P: the
// upper-diagonal halves of the PV pass's 256-row tiles (exp(0)=1 entries).
// Their colsum contribution is already in the diag tile's 128*ct seed.
__global__ __launch_bounds__(256) void ones_fill(short* __restrict__ P)
{
  const int r = blockIdx.x, bz = blockIdx.z;
  short* p = P + (long)bz * T_DIM * T_DIM +
             (long)(2 * r) * 128 * T_DIM + (2 * r + 1) * 128;
  const int t = threadIdx.x;
  const int row = t >> 1, c0 = (t & 1) * 64;
  bf16x8 ones;
#pragma unroll
  for (int j = 0; j < 8; ++j) ones[j] = (short)0x3F80;
#pragma unroll
  for (int j = 0; j < 8; ++j)
    *(bf16x8*)(p + (long)row * T_DIM + c0 + j * 8) = ones;
}

// fp32 -> bf16 elementwise (n multiple of 4)
__global__ __launch_bounds__(256) void f32_to_bf16(
    const float* __restrict__ src, short* __restrict__ dst, long n)
{
  long i = ((long)blockIdx.x * blockDim.x + threadIdx.x) * 4;
  if (i < n) {
    const float4 v = *(const float4*)(src + i);
    s16x4 o;
    o.x = f2bf(v.x); o.y = f2bf(v.y); o.z = f2bf(v.z); o.w = f2bf(v.w);
    *(s16x4*)(dst + i) = o;
  }
}

// W transpose: dst[c][r] = src_z[r][c], src fp32 [E,H] -> dst bf16 [H,E].
__global__ __launch_bounds__(256) void wtrans(
    const float* __restrict__ src0, const float* __restrict__ src1,
    short* __restrict__ dst)
{
  __shared__ short tile[64][65];
  const int t = threadIdx.x;
  const int c0 = blockIdx.x * 64;   // over H (dst rows)
  const int r0 = blockIdx.y * 64;   // over E
  const float* s = blockIdx.z ? src1 : src0;
  short* d = dst + (long)blockIdx.z * H_DIM * E_DIM;
  const int rl = t >> 4, cb = (t & 15) * 4;
#pragma unroll
  for (int i = 0; i < 4; ++i) {
    int r = rl + i * 16;
    const float4 w = *(const float4*)(s + (long)(r0 + r) * H_DIM + c0 + cb);
    tile[r][cb + 0] = f2bf(w.x); tile[r][cb + 1] = f2bf(w.y);
    tile[r][cb + 2] = f2bf(w.z); tile[r][cb + 3] = f2bf(w.w);
  }
  __syncthreads();
#pragma unroll
  for (int i = 0; i < 4; ++i) {
    int rr = rl + i * 16;
    s16x4 o;
    o.x = tile[cb + 0][rr]; o.y = tile[cb + 1][rr];
    o.z = tile[cb + 2][rr]; o.w = tile[cb + 3][rr];
    *(s16x4*)(d + (long)(c0 + rr) * E_DIM + r0 + cb) = o;
  }
}

// vT[h][k] = v[k][h] / sums[k]   (v bf16 [T,H] -> vT bf16 [H,T], per batch z)
__global__ __launch_bounds__(256) void vtrans(
    const short* __restrict__ src, short* __restrict__ dst,
    const float* __restrict__ sums)
{
  __shared__ short tile[64][65];
  const int t = threadIdx.x;
  const int c0 = blockIdx.x * 64;   // over H
  const int r0 = blockIdx.y * 64;   // over T (keys)
  const int bz = blockIdx.z;
  const short* s = src + (long)bz * T_DIM * H_DIM;
  short* d = dst + (long)bz * H_DIM * T_DIM;
  const float* su = sums + (long)bz * T_DIM;
  const int rl = t >> 4, cb = (t & 15) * 4;
#pragma unroll
  for (int i = 0; i < 4; ++i) {
    int r = rl + i * 16;
    const float rs = 1.0f / su[r0 + r];
    const s16x4 w = *(const s16x4*)(s + (long)(r0 + r) * H_DIM + c0 + cb);
    tile[r][cb + 0] = f2bf(bf2f(w.x) * rs); tile[r][cb + 1] = f2bf(bf2f(w.y) * rs);
    tile[r][cb + 2] = f2bf(bf2f(w.z) * rs); tile[r][cb + 3] = f2bf(bf2f(w.w) * rs);
  }
  __syncthreads();
#pragma unroll
  for (int i = 0; i < 4; ++i) {
    int rr = rl + i * 16;
    s16x4 o;
    o.x = tile[cb + 0][rr]; o.y = tile[cb + 1][rr];
    o.z = tile[cb + 2][rr]; o.w = tile[cb + 3][rr];
    *(s16x4*)(d + (long)(c0 + rr) * T_DIM + r0 + cb) = o;
  }
}

// psum[bz][j][h2] for 2 h-columns per thread (4B loads)
__global__ __launch_bounds__(256) void block_psum(
    const short* __restrict__ v, const float* __restrict__ colsum,
    float* __restrict__ psum)
{
  const int h = (blockIdx.x * 256 + threadIdx.x) * 2;
  const int j = blockIdx.y, bz = blockIdx.z;
  const short* vb = v + (long)bz * T_DIM * H_DIM;
  const float* cs = colsum + (long)bz * T_DIM;
  float s0 = 0.f, s1 = 0.f;
  const int k0 = j * 128;
  for (int k = k0; k < k0 + 128; ++k) {
    union { int i; short s[2]; } w;
    w.i = *(const int*)(vb + (long)k * H_DIM + h);
    const float rs = 1.0f / cs[k];
    s0 += bf2f(w.s[0]) * rs;
    s1 += bf2f(w.s[1]) * rs;
  }
  float* p = psum + ((long)bz * 16 + j) * H_DIM + h;
  p[0] = s0; p[1] = s1;
}

// sfx[bz][by][h] = sum_{j > by} psum[bz][j][h]
__global__ __launch_bounds__(256) void suffix_scan(
    const float* __restrict__ psum, float* __restrict__ sfx)
{
  const int h = blockIdx.x * 256 + threadIdx.x;
  const int bz = blockIdx.z;
  const long base = (long)bz * 16 * H_DIM + h;
  float suf = 0.f;
  sfx[base + 15L * H_DIM] = 0.f;
  for (int j = 15; j >= 1; --j) {
    suf += psum[base + (long)j * H_DIM];
    sfx[base + (long)(j - 1) * H_DIM] = suf;
  }
}

extern "C" void kernel_launch(void* const* d_in, const int* in_sizes, int n_in,
                              void* d_out, int out_size, void* d_ws, size_t ws_size,
                              hipStream_t stream) {
  const float* x  = (const float*)d_in[0];
  const float* Wq = (const float*)d_in[1];
  const float* bq = (const float*)d_in[2];
  const float* Wv = (const float*)d_in[3];
  const float* bv = (const float*)d_in[4];
  float* out = (float*)d_out;

  // d_ws layout (96 MiB + 544 KiB)
  char* ws = (char*)d_ws;
  short* P      = (short*)(ws);                                   // 32 MiB [B][T][T]
  short* q      = (short*)(ws + (size_t)32 * 1024 * 1024);        // 32 MiB [B*T][H]
  short* v      = (short*)(ws + (size_t)64 * 1024 * 1024);        // 32 MiB [B*T][H]
  float* colsum = (float*)(ws + (size_t)96 * 1024 * 1024);        // 32 KiB [B][T]
  float* sfx    = (float*)(ws + (size_t)96 * 1024 * 1024 + 32 * 1024);  // 512 KiB [B][16][H]
  short* vT = q;  // alias: q dead after the scores GEMM

  // d_out (64 MiB) doubles as scratch; all dead before PV GEMM writes d_out.
  short* xb    = (short*)d_out;                                     // 16 MiB [B*T][E]
  short* WqvT  = (short*)((char*)d_out + (size_t)16 * 1024 * 1024); //  8 MiB [2H][E]
  float* psum  = (float*)((char*)d_out + (size_t)24 * 1024 * 1024); // 512 KiB [B][16][H]

  const float scale = 0.022097086912079612f;  // 1/sqrt(2048)
  dim3 blk(256);

  hipMemsetAsync(colsum, 0, (size_t)B_DIM * T_DIM * 4, stream);

  // x -> bf16; Wq|Wv -> transposed bf16 [2H][E]
  f32_to_bf16<<<dim3((B_DIM * T_DIM * E_DIM) / (256 * 4)), blk, 0, stream>>>(
      x, xb, (long)B_DIM * T_DIM * E_DIM);
  wtrans<<<dim3(H_DIM / 64, E_DIM / 64, 2), blk, 0, stream>>>(Wq, Wv, WqvT);

  // fused projections: [q | v] = x @ WqvT^T + [bq | bv]  (M=8192, N=4096, K=1024)
  gemm256<0><<<dim3((2 * H_DIM) / 256, (B_DIM * T_DIM) / 256, 1), dim3(512), 0, stream>>>(
      xb, WqvT, bq, bv, q, v, nullptr, 2 * H_DIM, E_DIM, 0, 0, 0);

  // E = exp(mask(q q^T)/sqrt(H)): lower-triangular 128-tiles + colsum
  gemm_bt<1><<<dim3(136, 1, B_DIM), blk, 0, stream>>>(
      q, q, nullptr, nullptr, P, nullptr, colsum, nullptr, T_DIM, T_DIM, H_DIM,
      (long)T_DIM * H_DIM, (long)T_DIM * H_DIM, (long)T_DIM * T_DIM, scale);

  // upper-diagonal 128-tiles of the 256-row PV tiles are exp(0)=1
  ones_fill<<<dim3(8, 1, B_DIM), blk, 0, stream>>>(P);

  // vT[h][k] = v[k][h] / colsum[k]; suffix sums of v' over 128-key blocks
  vtrans<<<dim3(H_DIM / 64, T_DIM / 64, B_DIM), blk, 0, stream>>>(v, vT, colsum);
  block_psum<<<dim3(H_DIM / 512, 16, B_DIM), blk, 0, stream>>>(v, colsum, psum);
  suffix_scan<<<dim3(H_DIM / 256, 1, B_DIM), blk, 0, stream>>>(psum, sfx);

  // out = P(:, :K_end) @ v'(:K_end, :) + sfx[2rt+1]   (M=T, N=H, K=T) per batch
  gemm256<2><<<dim3(T_DIM / 256, H_DIM / 256, B_DIM), dim3(512), 0, stream>>>(
      P, vT, nullptr, nullptr, out, nullptr, sfx, H_DIM, T_DIM,
      (long)T_DIM * T_DIM, (long)H_DIM * T_DIM, (long)T_DIM * H_DIM);
}

// Round 2
// 359.033 us; speedup vs baseline: 1.0306x; 1.0007x over previous
//
#include <hip/hip_runtime.h>

// SelfAttnHead: B=4, T=2048, E=1024, H=2048. fp32 in/out, bf16 MFMA internally.
// out = softmax_axis1((q q^T / sqrt(H)) * tril) @ v,  q = x Wq + bq, v = x Wv + bv
// attn[q,k] = e[q,k]/s[k], e = exp(masked logits); masked (q<k) entries = exp(0) = 1.
// s[k] = column sum. Fold 1/s into v' = v/s. Triangular decomposition:
//   out[q,h] = sum_{k<K_end} P[q,k] v'[k,h] + sfx[h],  K_end=(rt+1)*256.
// Round 2: proj + PV GEMMs on the m201-style 8-phase 256x256 pipeline:
// BK=64, 2 LDS buffers, staging split into 4 sub-issues per K-tile (one
// K-half of one matrix per phase, 2 gloads), counted s_waitcnt vmcnt(4)
// retiring loads issued 4 phases earlier (vmcnt(0) only in the last tile),
// raw asm s_barrier (no drain), setprio(1) around each 16-MFMA cluster.
// LDS: K-half-contiguous, 128B fat-lines (row pair), slot = c ^ (f&7) —
// conflict-free b128 reads in 8-lane issue order. Scores stays on the
// verified 128^2 kernel this round.

#define B_DIM 4
#define T_DIM 2048
#define E_DIM 1024
#define H_DIM 2048

typedef __attribute__((ext_vector_type(8))) short bf16x8;
typedef __attribute__((ext_vector_type(4))) short s16x4;
typedef __attribute__((ext_vector_type(4))) float f32x4;

__device__ __forceinline__ float bf2f(short s) {
  union { float f; unsigned u; } x; x.u = ((unsigned)(unsigned short)s) << 16; return x.f;
}
__device__ __forceinline__ short f2bf(float f) {
  union { float f; unsigned u; } x; x.f = f;
  unsigned r = x.u + 0x7fff + ((x.u >> 16) & 1);  // RNE
  return (short)(r >> 16);
}

__device__ __forceinline__ void gload16(const short* g, short* l) {
  __builtin_amdgcn_global_load_lds(
      (const __attribute__((address_space(1))) void*)g,
      (__attribute__((address_space(3))) void*)l, 16, 0, 0);
}

// ============================================================================
// 256x256-tile 8-phase GEMM:  C[m,n] = sum_k A[m,k]*B[n,k]  (both row-major
// bf16 with K contiguous). 512 threads = 8 waves (2M x 4N), per-wave 128x64.
// BK=64; K-tile T in buf T&1. Per tile, 4 phases (s = kh*2 + mhalf):
//   s=0: read B_kh0 frags(4) + A_kh0 m0-3(4); stage A_kh0(T+1)
//   s=1: read A_kh0 m4-7(4);                  stage B_kh0(T+1)
//   s=2: read B_kh1(4) + A_kh1 m0-3(4);       stage A_kh1(T+1)
//   s=3: read A_kh1 m4-7(4);                  stage B_kh1(T+1)
// each phase: reads+stage -> barrier -> setprio(1) -> 16 MFMA -> setprio(0)
//   -> [s==1,3: vmcnt(4); last tile s==1: vmcnt(0)] -> barrier.
// LDS per buf: A[2kh][128 fat][64] | B same (32768 shorts). Fat-line f holds
// rows 2f,2f+1 (4 chunks each): slot = ((r&1)*4 + g) ^ (f&7).
// MODE 0: dual-output projection, grid (N/256, M/256), XCD-swizzled.
//         ct<8 -> Cg/bias else Cg2/bias2. bf16 out via swizzled LDS repack.
// MODE 2: fp32 out + sfx[2rt+1][col]; K-loop ends at (rt+1)*256.
//         grid (M/256, N/256, B) = 256 blocks, 1/CU.
// ============================================================================
template<int MODE>
__global__ __launch_bounds__(512, 2) void gemm256(
    const short* __restrict__ Ag, const short* __restrict__ Bg,
    const float* __restrict__ bias, const float* __restrict__ bias2,
    void* __restrict__ Cg, void* __restrict__ Cg2,
    const float* __restrict__ sfx,
    int N, int K, long sA, long sB, long sC)
{
  __shared__ __align__(16) short lds[2 * 32768];  // 128 KiB

  const int t = threadIdx.x;
  const int lane = t & 63, wave = t >> 6;
  const int wm = wave >> 2, wn = wave & 3;
  const int l16 = lane & 15, kg = lane >> 4;

  int rt, ct, bz;
  if (MODE == 2) { rt = blockIdx.x; ct = blockIdx.y; bz = blockIdx.z; }
  else {
    // bijective XCD swizzle (nwg = 512, divisible by 8)
    int lin = blockIdx.y * gridDim.x + blockIdx.x;
    const int cpx = (gridDim.x * gridDim.y) >> 3;
    lin = (lin & 7) * cpx + (lin >> 3);
    rt = lin / gridDim.x; ct = lin - rt * gridDim.x;
    bz = 0;
  }

  const short* A  = Ag + (long)bz * sA + (long)rt * 256 * K;
  const short* Bp = Bg + (long)bz * sB + (long)ct * 256 * K;
  const int kEnd = (MODE == 2) ? (rt + 1) * 256 : K;
  const int NT = kEnd >> 6;  // K-tiles of 64 (>= 4 for all uses)

  // staging: per sub (one matrix, one K-half = 8192 shorts), thread t does
  // cid = t and 512+t. f = cid>>3 (fat-line), slot = cid&7, c = slot^(f&7),
  // row = 2f + (c>>2), chunk g = c&3. Dest = cid*8 shorts (lane-contiguous).
  long soff[2];
  int dsto[2];
#pragma unroll
  for (int j = 0; j < 2; ++j) {
    const int cid = j * 512 + t;
    const int f = cid >> 3, sl = cid & 7;
    const int c = sl ^ (f & 7);
    soff[j] = (long)(2 * f + (c >> 2)) * K + (c & 3) * 8;
    dsto[j] = cid * 8;
  }

  // fragment reads: row r, chunk kg within a K-half:
  // f = r>>1, slot = ((r&1)*4 + kg) ^ (f&7); r = base + l16 with base%16==0
  // -> f&7 = (l16>>1)&7. 8-lane groups hit 8 distinct 16B slots (conflict-free).
  const int fl = l16 >> 1;
  const int slot = (((l16 & 1) * 4 + kg) ^ fl) & 7;
  const int aoff = (wm * 64 + fl) * 64 + slot * 8;   // within A K-half
  const int boff = (wn * 32 + fl) * 64 + slot * 8;   // within B K-half

  f32x4 acc[8][4] = {};

  // prologue: stage tile 0 fully; order = [A_kh0, B_kh0] x j, then kh1.
  {
    short* S = lds;
#pragma unroll
    for (int kh = 0; kh < 2; ++kh)
#pragma unroll
      for (int j = 0; j < 2; ++j) {
        gload16(A  + soff[j] + kh * 32, &S[kh * 8192 + dsto[j]]);
        gload16(Bp + soff[j] + kh * 32, &S[16384 + kh * 8192 + dsto[j]]);
      }
  }
  asm volatile("s_waitcnt vmcnt(4)" ::: "memory");  // kh0 pair landed
  asm volatile("s_barrier" ::: "memory");

  for (int T = 0; T < NT; ++T) {
    const short* Abase = lds + (T & 1) * 32768;
    short* S = lds + ((T + 1) & 1) * 32768;
    const long kIss = (long)(T + 1) * 64;
    const bool st = (T + 1) < NT;
    bf16x8 bfr[4], af[4];

    // ---- phase s=0: kh0, m0-3 ----
    {
      const short* Ab = Abase;
      const short* Bb = Abase + 16384;
#pragma unroll
      for (int n = 0; n < 4; ++n) bfr[n] = *(const bf16x8*)&Bb[boff + n * 512];
#pragma unroll
      for (int m = 0; m < 4; ++m) af[m] = *(const bf16x8*)&Ab[aoff + m * 512];
      if (st) {
        gload16(A + soff[0] + kIss, &S[dsto[0]]);
        gload16(A + soff[1] + kIss, &S[dsto[1]]);
      }
      asm volatile("s_barrier" ::: "memory");
      __builtin_amdgcn_s_setprio(1);
#pragma unroll
      for (int m = 0; m < 4; ++m)
#pragma unroll
        for (int n = 0; n < 4; ++n)
          acc[m][n] = __builtin_amdgcn_mfma_f32_16x16x32_bf16(af[m], bfr[n], acc[m][n], 0, 0, 0);
      __builtin_amdgcn_s_setprio(0);
      asm volatile("s_barrier" ::: "memory");
    }
    // ---- phase s=1: kh0, m4-7 ----
    {
      const short* Ab = Abase;
#pragma unroll
      for (int m = 0; m < 4; ++m) af[m] = *(const bf16x8*)&Ab[aoff + (m + 4) * 512];
      if (st) {
        gload16(Bp + soff[0] + kIss, &S[16384 + dsto[0]]);
        gload16(Bp + soff[1] + kIss, &S[16384 + dsto[1]]);
      }
      asm volatile("s_barrier" ::: "memory");
      __builtin_amdgcn_s_setprio(1);
#pragma unroll
      for (int m = 0; m < 4; ++m)
#pragma unroll
        for (int n = 0; n < 4; ++n)
          acc[m + 4][n] = __builtin_amdgcn_mfma_f32_16x16x32_bf16(af[m], bfr[n], acc[m + 4][n], 0, 0, 0);
      __builtin_amdgcn_s_setprio(0);
      if (T == NT - 1) asm volatile("s_waitcnt vmcnt(0)" ::: "memory");
      else             asm volatile("s_waitcnt vmcnt(4)" ::: "memory");
      asm volatile("s_barrier" ::: "memory");
    }
    // ---- phase s=2: kh1, m0-3 ----
    {
      const short* Ab = Abase + 8192;
      const short* Bb = Abase + 16384 + 8192;
#pragma unroll
      for (int n = 0; n < 4; ++n) bfr[n] = *(const bf16x8*)&Bb[boff + n * 512];
#pragma unroll
      for (int m = 0; m < 4; ++m) af[m] = *(const bf16x8*)&Ab[aoff + m * 512];
      if (st) {
        gload16(A + soff[0] + kIss + 32, &S[8192 + dsto[0]]);
        gload16(A + soff[1] + kIss + 32, &S[8192 + dsto[1]]);
      }
      asm volatile("s_barrier" ::: "memory");
      __builtin_amdgcn_s_setprio(1);
#pragma unroll
      for (int m = 0; m < 4; ++m)
#pragma unroll
        for (int n = 0; n < 4; ++n)
          acc[m][n] = __builtin_amdgcn_mfma_f32_16x16x32_bf16(af[m], bfr[n], acc[m][n], 0, 0, 0);
      __builtin_amdgcn_s_setprio(0);
      asm volatile("s_barrier" ::: "memory");
    }
    // ---- phase s=3: kh1, m4-7 ----
    {
      const short* Ab = Abase + 8192;
#pragma unroll
      for (int m = 0; m < 4; ++m) af[m] = *(const bf16x8*)&Ab[aoff + (m + 4) * 512];
      if (st) {
        gload16(Bp + soff[0] + kIss + 32, &S[16384 + 8192 + dsto[0]]);
        gload16(Bp + soff[1] + kIss + 32, &S[16384 + 8192 + dsto[1]]);
      }
      asm volatile("s_barrier" ::: "memory");
      __builtin_amdgcn_s_setprio(1);
#pragma unroll
      for (int m = 0; m < 4; ++m)
#pragma unroll
        for (int n = 0; n < 4; ++n)
          acc[m + 4][n] = __builtin_amdgcn_mfma_f32_16x16x32_bf16(af[m], bfr[n], acc[m + 4][n], 0, 0, 0);
      __builtin_amdgcn_s_setprio(0);
      if (st) asm volatile("s_waitcnt vmcnt(4)" ::: "memory");
      asm volatile("s_barrier" ::: "memory");
    }
  }

  __syncthreads();  // full drain before LDS reuse / exit

  if (MODE == 0) {
    // repack to bf16 in LDS (256x256 = 128 KiB), row-XOR swizzle so neither
    // the 2B scatter writes nor the b128 row reads 32-way conflict.
    short* Cs = lds;
    const int Nh = N >> 1;
#pragma unroll
    for (int m = 0; m < 8; ++m)
#pragma unroll
      for (int n = 0; n < 4; ++n) {
        const int cl = wn * 64 + n * 16 + l16;
        const int colg = ct * 256 + cl;
        const float bv = (colg < Nh) ? bias[colg] : bias2[colg - Nh];
#pragma unroll
        for (int r = 0; r < 4; ++r) {
          const int rl = wm * 128 + m * 16 + kg * 4 + r;
          *(short*)((char*)Cs + (((((rl << 8) + cl) << 1)) ^ ((rl & 7) << 4))) =
              f2bf(acc[m][n][r] + bv);
        }
      }
    __syncthreads();
    short* C = ((ct * 256) < Nh) ? (short*)Cg : (short*)Cg2;
    const int rr = t >> 1, hc = (t & 1) * 128;
    const long gbase = (long)(rt * 256 + rr) * Nh + ((ct * 256) & (Nh - 1)) + hc;
#pragma unroll
    for (int j = 0; j < 16; ++j)
      *(bf16x8*)(C + gbase + j * 8) =
          *(const bf16x8*)((const char*)Cs +
              ((((rr << 8) + hc + (j << 3)) << 1) ^ ((rr & 7) << 4)));
  } else {
    // fp32 direct stores (64B segments per l16 group) + suffix constant
    float* C = (float*)Cg + (long)bz * sC;
    const float* sf = sfx + ((long)bz * 16 + 2 * rt + 1) * N;
    const int rowb = rt * 256 + wm * 128 + kg * 4;
    const int colb = ct * 256 + wn * 64 + l16;
#pragma unroll
    for (int m = 0; m < 8; ++m)
#pragma unroll
      for (int n = 0; n < 4; ++n) {
        const int col = colb + n * 16;
        const float s = sf[col];
#pragma unroll
        for (int r = 0; r < 4; ++r)
          C[(long)(rowb + m * 16 + r) * N + col] = acc[m][n][r] + s;
      }
  }
}

// ============================================================================
// verified 128^2 kernel, kept for the scores pass (MODE 1)
// ============================================================================
template<int MODE>
__global__ __launch_bounds__(256) void gemm_bt(
    const short* __restrict__ Ag, const short* __restrict__ Bg,
    const float* __restrict__ bias, const float* __restrict__ bias2,
    void* __restrict__ Cg, void* __restrict__ Cg2,
    float* __restrict__ colsum, const float* __restrict__ sfx,
    int M, int N, int K, long sA, long sB, long sC, float scale)
{
  __shared__ __align__(16) short lds[128 * 64 * 2];  // As | Bs; reused as Cs
  short* As = lds;
  short* Bs = lds + 128 * 64;
  __shared__ float csum[128];

  const int t = threadIdx.x;
  const int bz = blockIdx.z;

  int rt, ct;
  if (MODE == 1) {
    int idx = 135 - blockIdx.x;  // heavy (large-rt) tiles dispatch first
    rt = (int)((sqrtf(8.0f * idx + 1.0f) - 1.0f) * 0.5f);
    while ((rt + 1) * (rt + 2) / 2 <= idx) rt++;
    while (rt * (rt + 1) / 2 > idx) rt--;
    ct = idx - rt * (rt + 1) / 2;
  } else {
    rt = blockIdx.y; ct = blockIdx.x;
  }

  const short* A = Ag + (long)bz * sA + (long)rt * 128 * K;
  const short* B = Bg + (long)bz * sB + (long)ct * 128 * K;
  const int kEnd = K;

  const int lane = t & 63;
  const int wave = t >> 6;
  const int wr = wave >> 1, wc = wave & 1;
  const int l16 = lane & 15, kg = lane >> 4;

  if (MODE == 1) { if (t < 128) csum[t] = (rt == ct) ? 128.0f * ct : 0.0f; }

  f32x4 acc[4][4] = {};

  for (int k0 = 0; k0 < kEnd; k0 += 64) {
    __syncthreads();
#pragma unroll
    for (int j = 0; j < 4; ++j) {
      const int e = j * 256 + t;
      const int r = e >> 3, cl = e & 7;
      const int cg = cl ^ (r & 7);
      gload16(A + (long)r * K + (k0 + cg * 8), &As[e * 8]);
      gload16(B + (long)r * K + (k0 + cg * 8), &Bs[e * 8]);
    }
    __syncthreads();
#pragma unroll
    for (int kk = 0; kk < 2; ++kk) {
      bf16x8 af[4], bfr[4];
#pragma unroll
      for (int mi = 0; mi < 4; ++mi)
        af[mi] = *(const bf16x8*)&As[(wr * 64 + mi * 16 + l16) * 64 +
                                     ((kk * 4 + kg) ^ (l16 & 7)) * 8];
#pragma unroll
      for (int ni = 0; ni < 4; ++ni)
        bfr[ni] = *(const bf16x8*)&Bs[(wc * 64 + ni * 16 + l16) * 64 +
                                      ((kk * 4 + kg) ^ (l16 & 7)) * 8];
#pragma unroll
      for (int mi = 0; mi < 4; ++mi)
#pragma unroll
        for (int ni = 0; ni < 4; ++ni)
          acc[mi][ni] = __builtin_amdgcn_mfma_f32_16x16x32_bf16(af[mi], bfr[ni], acc[mi][ni], 0, 0, 0);
    }
  }

  if (MODE == 1) {
    short* Cs = lds;  // 128x128 bf16 tile
    __syncthreads();
    float ps[4] = {0.f, 0.f, 0.f, 0.f};
#pragma unroll
    for (int mi = 0; mi < 4; ++mi)
#pragma unroll
      for (int ni = 0; ni < 4; ++ni) {
        const int cl = wc * 64 + ni * 16 + l16;
        const int col = ct * 128 + cl;
#pragma unroll
        for (int r = 0; r < 4; ++r) {
          const int rl = wr * 64 + kg * 4 + mi * 16 + r;
          const int row = rt * 128 + rl;
          float e = (row >= col) ? __expf(acc[mi][ni][r] * scale) : 1.0f;
          Cs[rl * 128 + cl] = f2bf(e);
          ps[ni] += e;
        }
      }
#pragma unroll
    for (int ni = 0; ni < 4; ++ni)
      atomicAdd(&csum[wc * 64 + ni * 16 + l16], ps[ni]);
    __syncthreads();
    short* C = (short*)Cg + (long)bz * sC;
    const int rr = t >> 1, cc = (t & 1) * 64;
    const long gbase = (long)(rt * 128 + rr) * N + ct * 128 + cc;
#pragma unroll
    for (int j = 0; j < 8; ++j)
      *(bf16x8*)(C + gbase + j * 8) = *(const bf16x8*)&Cs[rr * 128 + cc + j * 8];
    if (t < 128)
      atomicAdd(&colsum[(long)bz * N + ct * 128 + t], csum[t]);
  }
}

// all-ones 128x128 bf16 tiles at (row-tile 2r, col-tile 2r+1) of P: the
// upper-diagonal halves of the PV pass's 256-row tiles (exp(0)=1 entries).
// Their colsum contribution is already in the diag tile's 128*ct seed.
__global__ __launch_bounds__(256) void ones_fill(short* __restrict__ P)
{
  const int r = blockIdx.x, bz = blockIdx.z;
  short* p = P + (long)bz * T_DIM * T_DIM +
             (long)(2 * r) * 128 * T_DIM + (2 * r + 1) * 128;
  const int t = threadIdx.x;
  const int row = t >> 1, c0 = (t & 1) * 64;
  bf16x8 ones;
#pragma unroll
  for (int j = 0; j < 8; ++j) ones[j] = (short)0x3F80;
#pragma unroll
  for (int j = 0; j < 8; ++j)
    *(bf16x8*)(p + (long)row * T_DIM + c0 + j * 8) = ones;
}

// fp32 -> bf16 elementwise (n multiple of 4)
__global__ __launch_bounds__(256) void f32_to_bf16(
    const float* __restrict__ src, short* __restrict__ dst, long n)
{
  long i = ((long)blockIdx.x * blockDim.x + threadIdx.x) * 4;
  if (i < n) {
    const float4 v = *(const float4*)(src + i);
    s16x4 o;
    o.x = f2bf(v.x); o.y = f2bf(v.y); o.z = f2bf(v.z); o.w = f2bf(v.w);
    *(s16x4*)(dst + i) = o;
  }
}

// W transpose: dst[c][r] = src_z[r][c], src fp32 [E,H] -> dst bf16 [H,E].
__global__ __launch_bounds__(256) void wtrans(
    const float* __restrict__ src0, const float* __restrict__ src1,
    short* __restrict__ dst)
{
  __shared__ short tile[64][65];
  const int t = threadIdx.x;
  const int c0 = blockIdx.x * 64;   // over H (dst rows)
  const int r0 = blockIdx.y * 64;   // over E
  const float* s = blockIdx.z ? src1 : src0;
  short* d = dst + (long)blockIdx.z * H_DIM * E_DIM;
  const int rl = t >> 4, cb = (t & 15) * 4;
#pragma unroll
  for (int i = 0; i < 4; ++i) {
    int r = rl + i * 16;
    const float4 w = *(const float4*)(s + (long)(r0 + r) * H_DIM + c0 + cb);
    tile[r][cb + 0] = f2bf(w.x); tile[r][cb + 1] = f2bf(w.y);
    tile[r][cb + 2] = f2bf(w.z); tile[r][cb + 3] = f2bf(w.w);
  }
  __syncthreads();
#pragma unroll
  for (int i = 0; i < 4; ++i) {
    int rr = rl + i * 16;
    s16x4 o;
    o.x = tile[cb + 0][rr]; o.y = tile[cb + 1][rr];
    o.z = tile[cb + 2][rr]; o.w = tile[cb + 3][rr];
    *(s16x4*)(d + (long)(c0 + rr) * E_DIM + r0 + cb) = o;
  }
}

// vT[h][k] = v[k][h] / sums[k]   (v bf16 [T,H] -> vT bf16 [H,T], per batch z)
__global__ __launch_bounds__(256) void vtrans(
    const short* __restrict__ src, short* __restrict__ dst,
    const float* __restrict__ sums)
{
  __shared__ short tile[64][65];
  const int t = threadIdx.x;
  const int c0 = blockIdx.x * 64;   // over H
  const int r0 = blockIdx.y * 64;   // over T (keys)
  const int bz = blockIdx.z;
  const short* s = src + (long)bz * T_DIM * H_DIM;
  short* d = dst + (long)bz * H_DIM * T_DIM;
  const float* su = sums + (long)bz * T_DIM;
  const int rl = t >> 4, cb = (t & 15) * 4;
#pragma unroll
  for (int i = 0; i < 4; ++i) {
    int r = rl + i * 16;
    const float rs = 1.0f / su[r0 + r];
    const s16x4 w = *(const s16x4*)(s + (long)(r0 + r) * H_DIM + c0 + cb);
    tile[r][cb + 0] = f2bf(bf2f(w.x) * rs); tile[r][cb + 1] = f2bf(bf2f(w.y) * rs);
    tile[r][cb + 2] = f2bf(bf2f(w.z) * rs); tile[r][cb + 3] = f2bf(bf2f(w.w) * rs);
  }
  __syncthreads();
#pragma unroll
  for (int i = 0; i < 4; ++i) {
    int rr = rl + i * 16;
    s16x4 o;
    o.x = tile[cb + 0][rr]; o.y = tile[cb + 1][rr];
    o.z = tile[cb + 2][rr]; o.w = tile[cb + 3][rr];
    *(s16x4*)(d + (long)(c0 + rr) * T_DIM + r0 + cb) = o;
  }
}

// psum[bz][j][h2] for 2 h-columns per thread (4B loads)
__global__ __launch_bounds__(256) void block_psum(
    const short* __restrict__ v, const float* __restrict__ colsum,
    float* __restrict__ psum)
{
  const int h = (blockIdx.x * 256 + threadIdx.x) * 2;
  const int j = blockIdx.y, bz = blockIdx.z;
  const short* vb = v + (long)bz * T_DIM * H_DIM;
  const float* cs = colsum + (long)bz * T_DIM;
  float s0 = 0.f, s1 = 0.f;
  const int k0 = j * 128;
  for (int k = k0; k < k0 + 128; ++k) {
    union { int i; short s[2]; } w;
    w.i = *(const int*)(vb + (long)k * H_DIM + h);
    const float rs = 1.0f / cs[k];
    s0 += bf2f(w.s[0]) * rs;
    s1 += bf2f(w.s[1]) * rs;
  }
  float* p = psum + ((long)bz * 16 + j) * H_DIM + h;
  p[0] = s0; p[1] = s1;
}

// sfx[bz][by][h] = sum_{j > by} psum[bz][j][h]
__global__ __launch_bounds__(256) void suffix_scan(
    const float* __restrict__ psum, float* __restrict__ sfx)
{
  const int h = blockIdx.x * 256 + threadIdx.x;
  const int bz = blockIdx.z;
  const long base = (long)bz * 16 * H_DIM + h;
  float suf = 0.f;
  sfx[base + 15L * H_DIM] = 0.f;
  for (int j = 15; j >= 1; --j) {
    suf += psum[base + (long)j * H_DIM];
    sfx[base + (long)(j - 1) * H_DIM] = suf;
  }
}

extern "C" void kernel_launch(void* const* d_in, const int* in_sizes, int n_in,
                              void* d_out, int out_size, void* d_ws, size_t ws_size,
                              hipStream_t stream) {
  const float* x  = (const float*)d_in[0];
  const float* Wq = (const float*)d_in[1];
  const float* bq = (const float*)d_in[2];
  const float* Wv = (const float*)d_in[3];
  const float* bv = (const float*)d_in[4];
  float* out = (float*)d_out;

  // d_ws layout (96 MiB + 544 KiB)
  char* ws = (char*)d_ws;
  short* P      = (short*)(ws);                                   // 32 MiB [B][T][T]
  short* q      = (short*)(ws + (size_t)32 * 1024 * 1024);        // 32 MiB [B*T][H]
  short* v      = (short*)(ws + (size_t)64 * 1024 * 1024);        // 32 MiB [B*T][H]
  float* colsum = (float*)(ws + (size_t)96 * 1024 * 1024);        // 32 KiB [B][T]
  float* sfx    = (float*)(ws + (size_t)96 * 1024 * 1024 + 32 * 1024);  // 512 KiB [B][16][H]
  short* vT = q;  // alias: q dead after the scores GEMM

  // d_out (64 MiB) doubles as scratch; all dead before PV GEMM writes d_out.
  short* xb    = (short*)d_out;                                     // 16 MiB [B*T][E]
  short* WqvT  = (short*)((char*)d_out + (size_t)16 * 1024 * 1024); //  8 MiB [2H][E]
  float* psum  = (float*)((char*)d_out + (size_t)24 * 1024 * 1024); // 512 KiB [B][16][H]

  const float scale = 0.022097086912079612f;  // 1/sqrt(2048)
  dim3 blk(256);

  hipMemsetAsync(colsum, 0, (size_t)B_DIM * T_DIM * 4, stream);

  // x -> bf16; Wq|Wv -> transposed bf16 [2H][E]
  f32_to_bf16<<<dim3((B_DIM * T_DIM * E_DIM) / (256 * 4)), blk, 0, stream>>>(
      x, xb, (long)B_DIM * T_DIM * E_DIM);
  wtrans<<<dim3(H_DIM / 64, E_DIM / 64, 2), blk, 0, stream>>>(Wq, Wv, WqvT);

  // fused projections: [q | v] = x @ WqvT^T + [bq | bv]  (M=8192, N=4096, K=1024)
  gemm256<0><<<dim3((2 * H_DIM) / 256, (B_DIM * T_DIM) / 256, 1), dim3(512), 0, stream>>>(
      xb, WqvT, bq, bv, q, v, nullptr, 2 * H_DIM, E_DIM, 0, 0, 0);

  // E = exp(mask(q q^T)/sqrt(H)): lower-triangular 128-tiles + colsum
  gemm_bt<1><<<dim3(136, 1, B_DIM), blk, 0, stream>>>(
      q, q, nullptr, nullptr, P, nullptr, colsum, nullptr, T_DIM, T_DIM, H_DIM,
      (long)T_DIM * H_DIM, (long)T_DIM * H_DIM, (long)T_DIM * T_DIM, scale);

  // upper-diagonal 128-tiles of the 256-row PV tiles are exp(0)=1
  ones_fill<<<dim3(8, 1, B_DIM), blk, 0, stream>>>(P);

  // vT[h][k] = v[k][h] / colsum[k]; suffix sums of v' over 128-key blocks
  vtrans<<<dim3(H_DIM / 64, T_DIM / 64, B_DIM), blk, 0, stream>>>(v, vT, colsum);
  block_psum<<<dim3(H_DIM / 512, 16, B_DIM), blk, 0, stream>>>(v, colsum, psum);
  suffix_scan<<<dim3(H_DIM / 256, 1, B_DIM), blk, 0, stream>>>(psum, sfx);

  // out = P(:, :K_end) @ v'(:K_end, :) + sfx[2rt+1]   (M=T, N=H, K=T) per batch
  gemm256<2><<<dim3(T_DIM / 256, H_DIM / 256, B_DIM), dim3(512), 0, stream>>>(
      P, vT, nullptr, nullptr, out, nullptr, sfx, H_DIM, T_DIM,
      (long)T_DIM * T_DIM, (long)H_DIM * T_DIM, (long)T_DIM * H_DIM);
}

// Round 3
// 352.610 us; speedup vs baseline: 1.0493x; 1.0182x over previous
//
#include <hip/hip_runtime.h>

// SelfAttnHead: B=4, T=2048, E=1024, H=2048. fp32 in/out, bf16 MFMA internally.
// out = softmax_axis1((q q^T / sqrt(H)) * tril) @ v,  q = x Wq + bq, v = x Wv + bv
// attn[q,k] = e[q,k]/s[k], e = exp(masked logits); masked (q<k) entries = exp(0) = 1.
// s[k] = column sum. Fold 1/s into v' = v/s. Triangular decomposition:
//   out[q,h] = sum_{k<K_end} P[q,k] v'[k,h] + sfx[h],  K_end=(rt+1)*256.
// Round 3: same 256x256 8-phase pipeline as round 2, but with the sync ops
// fixed: round 2 used asm s_barrier with a "memory" clobber, which makes the
// backend insert s_waitcnt vmcnt(0) lgkmcnt(0) before EVERY barrier -> the
// counted-vmcnt pipeline was silently degraded to drain-per-phase (perf
// identical to round 0, m218's documented failure mode). Now: pure
// __builtin_amdgcn_s_barrier() (no drain), bare asm counted vmcnt waits,
// sched_barrier(0) pins so ds_reads can't hoist above the wait that covers
// their staging. Layout/staging/epilogues unchanged (refcheck'd in round 2).

#define B_DIM 4
#define T_DIM 2048
#define E_DIM 1024
#define H_DIM 2048

typedef __attribute__((ext_vector_type(8))) short bf16x8;
typedef __attribute__((ext_vector_type(4))) short s16x4;
typedef __attribute__((ext_vector_type(4))) float f32x4;

__device__ __forceinline__ float bf2f(short s) {
  union { float f; unsigned u; } x; x.u = ((unsigned)(unsigned short)s) << 16; return x.f;
}
__device__ __forceinline__ short f2bf(float f) {
  union { float f; unsigned u; } x; x.f = f;
  unsigned r = x.u + 0x7fff + ((x.u >> 16) & 1);  // RNE
  return (short)(r >> 16);
}

__device__ __forceinline__ void gload16(const short* g, short* l) {
  __builtin_amdgcn_global_load_lds(
      (const __attribute__((address_space(1))) void*)g,
      (__attribute__((address_space(3))) void*)l, 16, 0, 0);
}

// pure workgroup barrier, no waitcnt drain; sched_barrier pins code motion
__device__ __forceinline__ void bar() {
  __builtin_amdgcn_sched_barrier(0);
  __builtin_amdgcn_s_barrier();
  __builtin_amdgcn_sched_barrier(0);
}

// ============================================================================
// 256x256-tile 8-phase GEMM:  C[m,n] = sum_k A[m,k]*B[n,k]  (both row-major
// bf16 with K contiguous). 512 threads = 8 waves (2M x 4N), per-wave 128x64.
// BK=64; K-tile T in buf T&1. Per tile, 4 phases (s = kh*2 + mhalf):
//   s=0: read B_kh0 frags(4) + A_kh0 m0-3(4); stage A_kh0(T+1)
//   s=1: read A_kh0 m4-7(4);                  stage B_kh0(T+1)
//   s=2: read B_kh1(4) + A_kh1 m0-3(4);       stage A_kh1(T+1)
//   s=3: read A_kh1 m4-7(4);                  stage B_kh1(T+1)
// each phase: reads+stage -> bar -> setprio(1) -> 16 MFMA -> setprio(0)
//   -> [s==1,3: counted vmcnt(4); last-tile tail: vmcnt(0)] -> bar.
// vmcnt(4) retires loads issued 3-4 phases earlier; 4 loads stay in flight.
// LDS per buf: A[2kh][128 fat][64] | B same (32768 shorts). Fat-line f holds
// rows 2f,2f+1 (4 chunks each): slot = ((r&1)*4 + g) ^ (f&7) — conflict-free
// b128 reads (262K conflicts/dispatch measured, vs 6.5M unswizzled).
// MODE 0: dual-output projection, grid (N/256, M/256), XCD-swizzled.
//         ct<8 -> Cg/bias else Cg2/bias2. bf16 out via swizzled LDS repack.
// MODE 2: fp32 out + sfx[2rt+1][col]; K-loop ends at (rt+1)*256.
//         grid (M/256, N/256, B) = 256 blocks, 1/CU.
// ============================================================================
template<int MODE>
__global__ __launch_bounds__(512, 2) void gemm256(
    const short* __restrict__ Ag, const short* __restrict__ Bg,
    const float* __restrict__ bias, const float* __restrict__ bias2,
    void* __restrict__ Cg, void* __restrict__ Cg2,
    const float* __restrict__ sfx,
    int N, int K, long sA, long sB, long sC)
{
  __shared__ __align__(16) short lds[2 * 32768];  // 128 KiB

  const int t = threadIdx.x;
  const int lane = t & 63, wave = t >> 6;
  const int wm = wave >> 2, wn = wave & 3;
  const int l16 = lane & 15, kg = lane >> 4;

  int rt, ct, bz;
  if (MODE == 2) { rt = blockIdx.x; ct = blockIdx.y; bz = blockIdx.z; }
  else {
    // bijective XCD swizzle (nwg = 512, divisible by 8)
    int lin = blockIdx.y * gridDim.x + blockIdx.x;
    const int cpx = (gridDim.x * gridDim.y) >> 3;
    lin = (lin & 7) * cpx + (lin >> 3);
    rt = lin / gridDim.x; ct = lin - rt * gridDim.x;
    bz = 0;
  }

  const short* A  = Ag + (long)bz * sA + (long)rt * 256 * K;
  const short* Bp = Bg + (long)bz * sB + (long)ct * 256 * K;
  const int kEnd = (MODE == 2) ? (rt + 1) * 256 : K;
  const int NT = kEnd >> 6;  // K-tiles of 64 (>= 4 for all uses)

  // staging: per sub (one matrix, one K-half = 8192 shorts), thread t does
  // cid = t and 512+t. f = cid>>3 (fat-line), slot = cid&7, c = slot^(f&7),
  // row = 2f + (c>>2), chunk g = c&3. Dest = cid*8 shorts (lane-contiguous).
  long soff[2];
  int dsto[2];
#pragma unroll
  for (int j = 0; j < 2; ++j) {
    const int cid = j * 512 + t;
    const int f = cid >> 3, sl = cid & 7;
    const int c = sl ^ (f & 7);
    soff[j] = (long)(2 * f + (c >> 2)) * K + (c & 3) * 8;
    dsto[j] = cid * 8;
  }

  // fragment reads: row r, chunk kg within a K-half:
  // f = r>>1, slot = ((r&1)*4 + kg) ^ (f&7); r = base + l16 with base%16==0
  // -> f&7 = (l16>>1)&7. 8-lane groups hit 8 distinct 16B slots (conflict-free).
  const int fl = l16 >> 1;
  const int slot = (((l16 & 1) * 4 + kg) ^ fl) & 7;
  const int aoff = (wm * 64 + fl) * 64 + slot * 8;   // within A K-half
  const int boff = (wn * 32 + fl) * 64 + slot * 8;   // within B K-half

  f32x4 acc[8][4] = {};

  // prologue: stage tile 0 fully; order = [A_kh0, B_kh0] x j, then kh1.
  {
    short* S = lds;
#pragma unroll
    for (int kh = 0; kh < 2; ++kh)
#pragma unroll
      for (int j = 0; j < 2; ++j) {
        gload16(A  + soff[j] + kh * 32, &S[kh * 8192 + dsto[j]]);
        gload16(Bp + soff[j] + kh * 32, &S[16384 + kh * 8192 + dsto[j]]);
      }
  }
  asm volatile("s_waitcnt vmcnt(4)");  // kh0 pair landed
  __builtin_amdgcn_sched_barrier(0);
  bar();

  for (int T = 0; T < NT; ++T) {
    const short* Abase = lds + (T & 1) * 32768;
    short* S = lds + ((T + 1) & 1) * 32768;
    const long kIss = (long)(T + 1) * 64;
    const bool st = (T + 1) < NT;
    bf16x8 bfr[4], af[4];

    // ---- phase s=0: kh0, m0-3 ----
    {
      const short* Ab = Abase;
      const short* Bb = Abase + 16384;
#pragma unroll
      for (int n = 0; n < 4; ++n) bfr[n] = *(const bf16x8*)&Bb[boff + n * 512];
#pragma unroll
      for (int m = 0; m < 4; ++m) af[m] = *(const bf16x8*)&Ab[aoff + m * 512];
      if (st) {
        gload16(A + soff[0] + kIss, &S[dsto[0]]);
        gload16(A + soff[1] + kIss, &S[dsto[1]]);
      }
      bar();
      __builtin_amdgcn_s_setprio(1);
#pragma unroll
      for (int m = 0; m < 4; ++m)
#pragma unroll
        for (int n = 0; n < 4; ++n)
          acc[m][n] = __builtin_amdgcn_mfma_f32_16x16x32_bf16(af[m], bfr[n], acc[m][n], 0, 0, 0);
      __builtin_amdgcn_s_setprio(0);
      bar();
    }
    // ---- phase s=1: kh0, m4-7 ----
    {
      const short* Ab = Abase;
#pragma unroll
      for (int m = 0; m < 4; ++m) af[m] = *(const bf16x8*)&Ab[aoff + (m + 4) * 512];
      if (st) {
        gload16(Bp + soff[0] + kIss, &S[16384 + dsto[0]]);
        gload16(Bp + soff[1] + kIss, &S[16384 + dsto[1]]);
      }
      bar();
      __builtin_amdgcn_s_setprio(1);
#pragma unroll
      for (int m = 0; m < 4; ++m)
#pragma unroll
        for (int n = 0; n < 4; ++n)
          acc[m + 4][n] = __builtin_amdgcn_mfma_f32_16x16x32_bf16(af[m], bfr[n], acc[m + 4][n], 0, 0, 0);
      __builtin_amdgcn_s_setprio(0);
      // retire old kh1 stage-writes (consumed by s=2/s=3); keep 4 in flight
      if (T == NT - 1) asm volatile("s_waitcnt vmcnt(0)");
      else             asm volatile("s_waitcnt vmcnt(4)");
      __builtin_amdgcn_sched_barrier(0);
      bar();
    }
    // ---- phase s=2: kh1, m0-3 ----
    {
      const short* Ab = Abase + 8192;
      const short* Bb = Abase + 16384 + 8192;
#pragma unroll
      for (int n = 0; n < 4; ++n) bfr[n] = *(const bf16x8*)&Bb[boff + n * 512];
#pragma unroll
      for (int m = 0; m < 4; ++m) af[m] = *(const bf16x8*)&Ab[aoff + m * 512];
      if (st) {
        gload16(A + soff[0] + kIss + 32, &S[8192 + dsto[0]]);
        gload16(A + soff[1] + kIss + 32, &S[8192 + dsto[1]]);
      }
      bar();
      __builtin_amdgcn_s_setprio(1);
#pragma unroll
      for (int m = 0; m < 4; ++m)
#pragma unroll
        for (int n = 0; n < 4; ++n)
          acc[m][n] = __builtin_amdgcn_mfma_f32_16x16x32_bf16(af[m], bfr[n], acc[m][n], 0, 0, 0);
      __builtin_amdgcn_s_setprio(0);
      bar();
    }
    // ---- phase s=3: kh1, m4-7 ----
    {
      const short* Ab = Abase + 8192;
#pragma unroll
      for (int m = 0; m < 4; ++m) af[m] = *(const bf16x8*)&Ab[aoff + (m + 4) * 512];
      if (st) {
        gload16(Bp + soff[0] + kIss + 32, &S[16384 + 8192 + dsto[0]]);
        gload16(Bp + soff[1] + kIss + 32, &S[16384 + 8192 + dsto[1]]);
      }
      bar();
      __builtin_amdgcn_s_setprio(1);
#pragma unroll
      for (int m = 0; m < 4; ++m)
#pragma unroll
        for (int n = 0; n < 4; ++n)
          acc[m + 4][n] = __builtin_amdgcn_mfma_f32_16x16x32_bf16(af[m], bfr[n], acc[m + 4][n], 0, 0, 0);
      __builtin_amdgcn_s_setprio(0);
      // retire T+1's kh0 stage-writes (consumed by next s=0/s=1)
      if (st) {
        asm volatile("s_waitcnt vmcnt(4)");
        __builtin_amdgcn_sched_barrier(0);
      }
      bar();
    }
  }

  __syncthreads();  // full drain before LDS reuse / exit

  if (MODE == 0) {
    // repack to bf16 in LDS (256x256 = 128 KiB), row-XOR swizzle so neither
    // the 2B scatter writes nor the b128 row reads 32-way conflict.
    short* Cs = lds;
    const int Nh = N >> 1;
#pragma unroll
    for (int m = 0; m < 8; ++m)
#pragma unroll
      for (int n = 0; n < 4; ++n) {
        const int cl = wn * 64 + n * 16 + l16;
        const int colg = ct * 256 + cl;
        const float bv = (colg < Nh) ? bias[colg] : bias2[colg - Nh];
#pragma unroll
        for (int r = 0; r < 4; ++r) {
          const int rl = wm * 128 + m * 16 + kg * 4 + r;
          *(short*)((char*)Cs + (((((rl << 8) + cl) << 1)) ^ ((rl & 7) << 4))) =
              f2bf(acc[m][n][r] + bv);
        }
      }
    __syncthreads();
    short* C = ((ct * 256) < Nh) ? (short*)Cg : (short*)Cg2;
    const int rr = t >> 1, hc = (t & 1) * 128;
    const long gbase = (long)(rt * 256 + rr) * Nh + ((ct * 256) & (Nh - 1)) + hc;
#pragma unroll
    for (int j = 0; j < 16; ++j)
      *(bf16x8*)(C + gbase + j * 8) =
          *(const bf16x8*)((const char*)Cs +
              ((((rr << 8) + hc + (j << 3)) << 1) ^ ((rr & 7) << 4)));
  } else {
    // fp32 direct stores (64B segments per l16 group) + suffix constant
    float* C = (float*)Cg + (long)bz * sC;
    const float* sf = sfx + ((long)bz * 16 + 2 * rt + 1) * N;
    const int rowb = rt * 256 + wm * 128 + kg * 4;
    const int colb = ct * 256 + wn * 64 + l16;
#pragma unroll
    for (int m = 0; m < 8; ++m)
#pragma unroll
      for (int n = 0; n < 4; ++n) {
        const int col = colb + n * 16;
        const float s = sf[col];
#pragma unroll
        for (int r = 0; r < 4; ++r)
          C[(long)(rowb + m * 16 + r) * N + col] = acc[m][n][r] + s;
      }
  }
}

// ============================================================================
// verified 128^2 kernel, kept for the scores pass (MODE 1)
// ============================================================================
template<int MODE>
__global__ __launch_bounds__(256) void gemm_bt(
    const short* __restrict__ Ag, const short* __restrict__ Bg,
    const float* __restrict__ bias, const float* __restrict__ bias2,
    void* __restrict__ Cg, void* __restrict__ Cg2,
    float* __restrict__ colsum, const float* __restrict__ sfx,
    int M, int N, int K, long sA, long sB, long sC, float scale)
{
  __shared__ __align__(16) short lds[128 * 64 * 2];  // As | Bs; reused as Cs
  short* As = lds;
  short* Bs = lds + 128 * 64;
  __shared__ float csum[128];

  const int t = threadIdx.x;
  const int bz = blockIdx.z;

  int rt, ct;
  if (MODE == 1) {
    int idx = 135 - blockIdx.x;  // heavy (large-rt) tiles dispatch first
    rt = (int)((sqrtf(8.0f * idx + 1.0f) - 1.0f) * 0.5f);
    while ((rt + 1) * (rt + 2) / 2 <= idx) rt++;
    while (rt * (rt + 1) / 2 > idx) rt--;
    ct = idx - rt * (rt + 1) / 2;
  } else {
    rt = blockIdx.y; ct = blockIdx.x;
  }

  const short* A = Ag + (long)bz * sA + (long)rt * 128 * K;
  const short* B = Bg + (long)bz * sB + (long)ct * 128 * K;
  const int kEnd = K;

  const int lane = t & 63;
  const int wave = t >> 6;
  const int wr = wave >> 1, wc = wave & 1;
  const int l16 = lane & 15, kg = lane >> 4;

  if (MODE == 1) { if (t < 128) csum[t] = (rt == ct) ? 128.0f * ct : 0.0f; }

  f32x4 acc[4][4] = {};

  for (int k0 = 0; k0 < kEnd; k0 += 64) {
    __syncthreads();
#pragma unroll
    for (int j = 0; j < 4; ++j) {
      const int e = j * 256 + t;
      const int r = e >> 3, cl = e & 7;
      const int cg = cl ^ (r & 7);
      gload16(A + (long)r * K + (k0 + cg * 8), &As[e * 8]);
      gload16(B + (long)r * K + (k0 + cg * 8), &Bs[e * 8]);
    }
    __syncthreads();
#pragma unroll
    for (int kk = 0; kk < 2; ++kk) {
      bf16x8 af[4], bfr[4];
#pragma unroll
      for (int mi = 0; mi < 4; ++mi)
        af[mi] = *(const bf16x8*)&As[(wr * 64 + mi * 16 + l16) * 64 +
                                     ((kk * 4 + kg) ^ (l16 & 7)) * 8];
#pragma unroll
      for (int ni = 0; ni < 4; ++ni)
        bfr[ni] = *(const bf16x8*)&Bs[(wc * 64 + ni * 16 + l16) * 64 +
                                      ((kk * 4 + kg) ^ (l16 & 7)) * 8];
#pragma unroll
      for (int mi = 0; mi < 4; ++mi)
#pragma unroll
        for (int ni = 0; ni < 4; ++ni)
          acc[mi][ni] = __builtin_amdgcn_mfma_f32_16x16x32_bf16(af[mi], bfr[ni], acc[mi][ni], 0, 0, 0);
    }
  }

  if (MODE == 1) {
    short* Cs = lds;  // 128x128 bf16 tile
    __syncthreads();
    float ps[4] = {0.f, 0.f, 0.f, 0.f};
#pragma unroll
    for (int mi = 0; mi < 4; ++mi)
#pragma unroll
      for (int ni = 0; ni < 4; ++ni) {
        const int cl = wc * 64 + ni * 16 + l16;
        const int col = ct * 128 + cl;
#pragma unroll
        for (int r = 0; r < 4; ++r) {
          const int rl = wr * 64 + kg * 4 + mi * 16 + r;
          const int row = rt * 128 + rl;
          float e = (row >= col) ? __expf(acc[mi][ni][r] * scale) : 1.0f;
          Cs[rl * 128 + cl] = f2bf(e);
          ps[ni] += e;
        }
      }
#pragma unroll
    for (int ni = 0; ni < 4; ++ni)
      atomicAdd(&csum[wc * 64 + ni * 16 + l16], ps[ni]);
    __syncthreads();
    short* C = (short*)Cg + (long)bz * sC;
    const int rr = t >> 1, cc = (t & 1) * 64;
    const long gbase = (long)(rt * 128 + rr) * N + ct * 128 + cc;
#pragma unroll
    for (int j = 0; j < 8; ++j)
      *(bf16x8*)(C + gbase + j * 8) = *(const bf16x8*)&Cs[rr * 128 + cc + j * 8];
    if (t < 128)
      atomicAdd(&colsum[(long)bz * N + ct * 128 + t], csum[t]);
  }
}

// all-ones 128x128 bf16 tiles at (row-tile 2r, col-tile 2r+1) of P: the
// upper-diagonal halves of the PV pass's 256-row tiles (exp(0)=1 entries).
// Their colsum contribution is already in the diag tile's 128*ct seed.
__global__ __launch_bounds__(256) void ones_fill(short* __restrict__ P)
{
  const int r = blockIdx.x, bz = blockIdx.z;
  short* p = P + (long)bz * T_DIM * T_DIM +
             (long)(2 * r) * 128 * T_DIM + (2 * r + 1) * 128;
  const int t = threadIdx.x;
  const int row = t >> 1, c0 = (t & 1) * 64;
  bf16x8 ones;
#pragma unroll
  for (int j = 0; j < 8; ++j) ones[j] = (short)0x3F80;
#pragma unroll
  for (int j = 0; j < 8; ++j)
    *(bf16x8*)(p + (long)row * T_DIM + c0 + j * 8) = ones;
}

// fp32 -> bf16 elementwise (n multiple of 4)
__global__ __launch_bounds__(256) void f32_to_bf16(
    const float* __restrict__ src, short* __restrict__ dst, long n)
{
  long i = ((long)blockIdx.x * blockDim.x + threadIdx.x) * 4;
  if (i < n) {
    const float4 v = *(const float4*)(src + i);
    s16x4 o;
    o.x = f2bf(v.x); o.y = f2bf(v.y); o.z = f2bf(v.z); o.w = f2bf(v.w);
    *(s16x4*)(dst + i) = o;
  }
}

// W transpose: dst[c][r] = src_z[r][c], src fp32 [E,H] -> dst bf16 [H,E].
__global__ __launch_bounds__(256) void wtrans(
    const float* __restrict__ src0, const float* __restrict__ src1,
    short* __restrict__ dst)
{
  __shared__ short tile[64][65];
  const int t = threadIdx.x;
  const int c0 = blockIdx.x * 64;   // over H (dst rows)
  const int r0 = blockIdx.y * 64;   // over E
  const float* s = blockIdx.z ? src1 : src0;
  short* d = dst + (long)blockIdx.z * H_DIM * E_DIM;
  const int rl = t >> 4, cb = (t & 15) * 4;
#pragma unroll
  for (int i = 0; i < 4; ++i) {
    int r = rl + i * 16;
    const float4 w = *(const float4*)(s + (long)(r0 + r) * H_DIM + c0 + cb);
    tile[r][cb + 0] = f2bf(w.x); tile[r][cb + 1] = f2bf(w.y);
    tile[r][cb + 2] = f2bf(w.z); tile[r][cb + 3] = f2bf(w.w);
  }
  __syncthreads();
#pragma unroll
  for (int i = 0; i < 4; ++i) {
    int rr = rl + i * 16;
    s16x4 o;
    o.x = tile[cb + 0][rr]; o.y = tile[cb + 1][rr];
    o.z = tile[cb + 2][rr]; o.w = tile[cb + 3][rr];
    *(s16x4*)(d + (long)(c0 + rr) * E_DIM + r0 + cb) = o;
  }
}

// vT[h][k] = v[k][h] / sums[k]   (v bf16 [T,H] -> vT bf16 [H,T], per batch z)
__global__ __launch_bounds__(256) void vtrans(
    const short* __restrict__ src, short* __restrict__ dst,
    const float* __restrict__ sums)
{
  __shared__ short tile[64][65];
  const int t = threadIdx.x;
  const int c0 = blockIdx.x * 64;   // over H
  const int r0 = blockIdx.y * 64;   // over T (keys)
  const int bz = blockIdx.z;
  const short* s = src + (long)bz * T_DIM * H_DIM;
  short* d = dst + (long)bz * H_DIM * T_DIM;
  const float* su = sums + (long)bz * T_DIM;
  const int rl = t >> 4, cb = (t & 15) * 4;
#pragma unroll
  for (int i = 0; i < 4; ++i) {
    int r = rl + i * 16;
    const float rs = 1.0f / su[r0 + r];
    const s16x4 w = *(const s16x4*)(s + (long)(r0 + r) * H_DIM + c0 + cb);
    tile[r][cb + 0] = f2bf(bf2f(w.x) * rs); tile[r][cb + 1] = f2bf(bf2f(w.y) * rs);
    tile[r][cb + 2] = f2bf(bf2f(w.z) * rs); tile[r][cb + 3] = f2bf(bf2f(w.w) * rs);
  }
  __syncthreads();
#pragma unroll
  for (int i = 0; i < 4; ++i) {
    int rr = rl + i * 16;
    s16x4 o;
    o.x = tile[cb + 0][rr]; o.y = tile[cb + 1][rr];
    o.z = tile[cb + 2][rr]; o.w = tile[cb + 3][rr];
    *(s16x4*)(d + (long)(c0 + rr) * T_DIM + r0 + cb) = o;
  }
}

// psum[bz][j][h2] for 2 h-columns per thread (4B loads)
__global__ __launch_bounds__(256) void block_psum(
    const short* __restrict__ v, const float* __restrict__ colsum,
    float* __restrict__ psum)
{
  const int h = (blockIdx.x * 256 + threadIdx.x) * 2;
  const int j = blockIdx.y, bz = blockIdx.z;
  const short* vb = v + (long)bz * T_DIM * H_DIM;
  const float* cs = colsum + (long)bz * T_DIM;
  float s0 = 0.f, s1 = 0.f;
  const int k0 = j * 128;
  for (int k = k0; k < k0 + 128; ++k) {
    union { int i; short s[2]; } w;
    w.i = *(const int*)(vb + (long)k * H_DIM + h);
    const float rs = 1.0f / cs[k];
    s0 += bf2f(w.s[0]) * rs;
    s1 += bf2f(w.s[1]) * rs;
  }
  float* p = psum + ((long)bz * 16 + j) * H_DIM + h;
  p[0] = s0; p[1] = s1;
}

// sfx[bz][by][h] = sum_{j > by} psum[bz][j][h]
__global__ __launch_bounds__(256) void suffix_scan(
    const float* __restrict__ psum, float* __restrict__ sfx)
{
  const int h = blockIdx.x * 256 + threadIdx.x;
  const int bz = blockIdx.z;
  const long base = (long)bz * 16 * H_DIM + h;
  float suf = 0.f;
  sfx[base + 15L * H_DIM] = 0.f;
  for (int j = 15; j >= 1; --j) {
    suf += psum[base + (long)j * H_DIM];
    sfx[base + (long)(j - 1) * H_DIM] = suf;
  }
}

extern "C" void kernel_launch(void* const* d_in, const int* in_sizes, int n_in,
                              void* d_out, int out_size, void* d_ws, size_t ws_size,
                              hipStream_t stream) {
  const float* x  = (const float*)d_in[0];
  const float* Wq = (const float*)d_in[1];
  const float* bq = (const float*)d_in[2];
  const float* Wv = (const float*)d_in[3];
  const float* bv = (const float*)d_in[4];
  float* out = (float*)d_out;

  // d_ws layout (96 MiB + 544 KiB)
  char* ws = (char*)d_ws;
  short* P      = (short*)(ws);                                   // 32 MiB [B][T][T]
  short* q      = (short*)(ws + (size_t)32 * 1024 * 1024);        // 32 MiB [B*T][H]
  short* v      = (short*)(ws + (size_t)64 * 1024 * 1024);        // 32 MiB [B*T][H]
  float* colsum = (float*)(ws + (size_t)96 * 1024 * 1024);        // 32 KiB [B][T]
  float* sfx    = (float*)(ws + (size_t)96 * 1024 * 1024 + 32 * 1024);  // 512 KiB [B][16][H]
  short* vT = q;  // alias: q dead after the scores GEMM

  // d_out (64 MiB) doubles as scratch; all dead before PV GEMM writes d_out.
  short* xb    = (short*)d_out;                                     // 16 MiB [B*T][E]
  short* WqvT  = (short*)((char*)d_out + (size_t)16 * 1024 * 1024); //  8 MiB [2H][E]
  float* psum  = (float*)((char*)d_out + (size_t)24 * 1024 * 1024); // 512 KiB [B][16][H]

  const float scale = 0.022097086912079612f;  // 1/sqrt(2048)
  dim3 blk(256);

  hipMemsetAsync(colsum, 0, (size_t)B_DIM * T_DIM * 4, stream);

  // x -> bf16; Wq|Wv -> transposed bf16 [2H][E]
  f32_to_bf16<<<dim3((B_DIM * T_DIM * E_DIM) / (256 * 4)), blk, 0, stream>>>(
      x, xb, (long)B_DIM * T_DIM * E_DIM);
  wtrans<<<dim3(H_DIM / 64, E_DIM / 64, 2), blk, 0, stream>>>(Wq, Wv, WqvT);

  // fused projections: [q | v] = x @ WqvT^T + [bq | bv]  (M=8192, N=4096, K=1024)
  gemm256<0><<<dim3((2 * H_DIM) / 256, (B_DIM * T_DIM) / 256, 1), dim3(512), 0, stream>>>(
      xb, WqvT, bq, bv, q, v, nullptr, 2 * H_DIM, E_DIM, 0, 0, 0);

  // E = exp(mask(q q^T)/sqrt(H)): lower-triangular 128-tiles + colsum
  gemm_bt<1><<<dim3(136, 1, B_DIM), blk, 0, stream>>>(
      q, q, nullptr, nullptr, P, nullptr, colsum, nullptr, T_DIM, T_DIM, H_DIM,
      (long)T_DIM * H_DIM, (long)T_DIM * H_DIM, (long)T_DIM * T_DIM, scale);

  // upper-diagonal 128-tiles of the 256-row PV tiles are exp(0)=1
  ones_fill<<<dim3(8, 1, B_DIM), blk, 0, stream>>>(P);

  // vT[h][k] = v[k][h] / colsum[k]; suffix sums of v' over 128-key blocks
  vtrans<<<dim3(H_DIM / 64, T_DIM / 64, B_DIM), blk, 0, stream>>>(v, vT, colsum);
  block_psum<<<dim3(H_DIM / 512, 16, B_DIM), blk, 0, stream>>>(v, colsum, psum);
  suffix_scan<<<dim3(H_DIM / 256, 1, B_DIM), blk, 0, stream>>>(psum, sfx);

  // out = P(:, :K_end) @ v'(:K_end, :) + sfx[2rt+1]   (M=T, N=H, K=T) per batch
  gemm256<2><<<dim3(T_DIM / 256, H_DIM / 256, B_DIM), dim3(512), 0, stream>>>(
      P, vT, nullptr, nullptr, out, nullptr, sfx, H_DIM, T_DIM,
      (long)T_DIM * T_DIM, (long)H_DIM * T_DIM, (long)T_DIM * H_DIM);
}